// Round 1
// 974.396 us; speedup vs baseline: 1.0135x; 1.0135x over previous
//
#include <hip/hip_runtime.h>
#include <hip/hip_bf16.h>

// WaveOperator: Fourier-domain 3-term recurrence + per-row inverse FFT sampling.
// A_{t+1}(p,q) = (2-4*fil(p,q)) * A_t - A_{t-1};  y[b,j,t] = Re(ifft2(A_{t+1})[u_j,v_j])
// R18: replace the T1/T2 LDS round-trip transposes inside the 512-pt four-step FFT with
// in-register digit exchanges (permlane16/32_swap + DPP row_ror:8/quad_perm + one ds_swizzle
// stage for xor4). Prior best (R15/R17, 987us) was LDS-pipe bound (~80% busy, 1.44e8 conflict
// cycles); T1/T2 were pure intra-wave 8x8 transposes = reg-digit <-> lane-digit exchanges,
// which gfx950 can do on the VALU pipe. Twiddles (tA/tB), final publish layout and spos are
// IDENTICAL to R15 (verified digit bookkeeping) -> bit-exact same arithmetic, less LDS.
// Remaining LDS per wave-step: 8 ds_swizzle + 4 ds_write_b128 (publish) + sensor gather.

#define NOUT 512
#define NB 16
#define NPHI 256
#define NT 240
#define RPB 6             // rows per block (= waves per block)
#define NGRP 43           // row groups: 43*6 = 258 = rows 0..257 (257 gets zero phase)

#define WREG 5184         // per-wave LDS publish region (pitch 80 -> 5120 used)

typedef float v2f __attribute__((ext_vector_type(2)));
typedef float v4f __attribute__((ext_vector_type(4)));
typedef unsigned int v2u __attribute__((ext_vector_type(2)));

__device__ __forceinline__ v2f cmulv(v2f a, v2f b) {
    return v2f{fmaf(a.x, b.x, -a.y * b.y), fmaf(a.x, b.y, a.y * b.x)};
}
__device__ __forceinline__ v2f cmuliv(v2f a) { return v2f{-a.y, a.x}; }
__device__ __forceinline__ v2f cmulw8v(v2f a) {
    const float s = 0.70710678118654752f; return v2f{s * (a.x - a.y), s * (a.x + a.y)};
}
__device__ __forceinline__ v2f cmulw83v(v2f a) {
    const float s = 0.70710678118654752f; return v2f{-s * (a.x + a.y), s * (a.x - a.y)};
}

// 8-pt DFT, positive exponent: Y[k] = sum_r y[r] * exp(+2pi i rk/8)
__device__ __forceinline__ void dft8p(const v2f y[8], v2f Y[8]) {
    v2f t0 = y[0] + y[4], t4 = y[0] - y[4];
    v2f t1 = y[1] + y[5], t5 = cmulw8v(y[1] - y[5]);
    v2f t2 = y[2] + y[6], t6 = cmuliv(y[2] - y[6]);
    v2f t3 = y[3] + y[7], t7 = cmulw83v(y[3] - y[7]);
    v2f u0 = t0 + t2, u2 = t0 - t2;
    v2f u1 = t1 + t3, u3 = cmuliv(t1 - t3);
    Y[0] = u0 + u1; Y[4] = u0 - u1;
    Y[2] = u2 + u3; Y[6] = u2 - u3;
    v2f v0 = t4 + t6, v2 = t4 - t6;
    v2f v1 = t5 + t7, v3 = cmuliv(t5 - t7);
    Y[1] = v0 + v1; Y[5] = v0 - v1;
    Y[3] = v2 + v3; Y[7] = v2 - v3;
}

// in-place variant (t-layer fully buffers the inputs before any write)
__device__ __forceinline__ void dft8p_ip(v2f y[8]) {
    v2f t0 = y[0] + y[4], t4 = y[0] - y[4];
    v2f t1 = y[1] + y[5], t5 = cmulw8v(y[1] - y[5]);
    v2f t2 = y[2] + y[6], t6 = cmuliv(y[2] - y[6]);
    v2f t3 = y[3] + y[7], t7 = cmulw83v(y[3] - y[7]);
    v2f u0 = t0 + t2, u2 = t0 - t2;
    v2f u1 = t1 + t3, u3 = cmuliv(t1 - t3);
    y[0] = u0 + u1; y[4] = u0 - u1;
    y[2] = u2 + u3; y[6] = u2 - u3;
    v2f v0 = t4 + t6, v2 = t4 - t6;
    v2f v1 = t5 + t7, v3 = cmuliv(t5 - t7);
    y[1] = v0 + v1; y[5] = v0 - v1;
    y[3] = v2 + v3; y[7] = v2 - v3;
}

// W512^m from half-table
__device__ __forceinline__ v2f wlookup(const float2* trig, int m) {
    m &= 511;
    float2 ph = trig[m & 255];
    return (m & 256) ? v2f{-ph.x, -ph.y} : v2f{ph.x, ph.y};
}

// ---- in-register lane exchanges (transpose building blocks) -------------------------------------
// DPP full-lane xor shuffle (quad_perm / row_ror patterns); compiler handles DPP hazards.
template<int CTRL>
__device__ __forceinline__ float dppx(float x) {
    return __int_as_float(__builtin_amdgcn_mov_dpp(__float_as_int(x), CTRL, 0xF, 0xF, true));
}
__device__ __forceinline__ float swzx4(float x) {
    // BitMode swizzle: and=0x1F, or=0, xor=4  -> lane ^ 4 (within 32-lane halves; mask<32 ok)
    return __int_as_float(__builtin_amdgcn_ds_swizzle(__float_as_int(x), 0x101F));
}

// Exchange register pair (a,b) across lane mask m (via shuffle prim S): implements the
// (reg-bit <-> lane-bit) swap.  bit = (lane & m) != 0.
template<int CTRL>
__device__ __forceinline__ void xchg_dpp(v2f& a, v2f& b, bool bit) {
    float sx = bit ? a.x : b.x;
    float sy = bit ? a.y : b.y;
    float tx = dppx<CTRL>(sx);
    float ty = dppx<CTRL>(sy);
    a.x = bit ? tx : a.x;   a.y = bit ? ty : a.y;
    b.x = bit ? b.x : tx;   b.y = bit ? b.y : ty;
}
__device__ __forceinline__ void xchg_swz4(v2f& a, v2f& b, bool bit) {
    float sx = bit ? a.x : b.x;
    float sy = bit ? a.y : b.y;
    float tx = swzx4(sx);
    float ty = swzx4(sy);
    a.x = bit ? tx : a.x;   a.y = bit ? ty : a.y;
    b.x = bit ? b.x : tx;   b.y = bit ? b.y : ty;
}

#if __has_builtin(__builtin_amdgcn_permlane16_swap)
__device__ __forceinline__ void pl16x(v2f& a, v2f& b) {
    v2u rx = __builtin_amdgcn_permlane16_swap(__float_as_uint(a.x), __float_as_uint(b.x), false, false);
    a.x = __uint_as_float(rx.x); b.x = __uint_as_float(rx.y);
    v2u ry = __builtin_amdgcn_permlane16_swap(__float_as_uint(a.y), __float_as_uint(b.y), false, false);
    a.y = __uint_as_float(ry.x); b.y = __uint_as_float(ry.y);
}
#else
__device__ __forceinline__ void pl16x(v2f& a, v2f& b) {
    bool bit = (threadIdx.x & 16) != 0;
    float sx = bit ? a.x : b.x, sy = bit ? a.y : b.y;
    float tx = __shfl_xor(sx, 16), ty = __shfl_xor(sy, 16);
    a.x = bit ? tx : a.x; a.y = bit ? ty : a.y;
    b.x = bit ? b.x : tx; b.y = bit ? b.y : ty;
}
#endif

#if __has_builtin(__builtin_amdgcn_permlane32_swap)
__device__ __forceinline__ void pl32x(v2f& a, v2f& b) {
    v2u rx = __builtin_amdgcn_permlane32_swap(__float_as_uint(a.x), __float_as_uint(b.x), false, false);
    a.x = __uint_as_float(rx.x); b.x = __uint_as_float(rx.y);
    v2u ry = __builtin_amdgcn_permlane32_swap(__float_as_uint(a.y), __float_as_uint(b.y), false, false);
    a.y = __uint_as_float(ry.x); b.y = __uint_as_float(ry.y);
}
#else
__device__ __forceinline__ void pl32x(v2f& a, v2f& b) {
    bool bit = (threadIdx.x & 32) != 0;
    float sx = bit ? a.x : b.x, sy = bit ? a.y : b.y;
    float tx = __shfl_xor(sx, 32), ty = __shfl_xor(sy, 32);
    a.x = bit ? tx : a.x; a.y = bit ? ty : a.y;
    b.x = bit ? b.x : tx; b.y = bit ? b.y : ty;
}
#endif

// hot-loop step: fully in-register 512-pt inverse DFT (8x8x8 four-step; transposes via
// permlane/DPP/swizzle), then the cross-wave sample: barrier alpha guards publish-region
// reuse, barrier beta publishes T.
__device__ __forceinline__ void fft_sample(
    const v2f y[8], const v2f tA[8], const v2f tB[8],
    bool b0, bool b1, bool b2, bool b3,
    char* awBase, const char* ldsBase, int spos, const v2f ph[RPB], bool active,
    float* pA)
{
    v2f G[8];
    dft8p(y, G);                                   // DFT over q2 (reg digit) -> v0
#pragma unroll
    for (int k1 = 1; k1 < 8; ++k1) G[k1] = cmulv(G[k1], tA[k1]);   // W512^{L*v0}
    // T1: reg digit (v0) <-> lane-high digit (q1): bits reg0<->lane3, reg1<->lane4, reg2<->lane5
    xchg_dpp<0x128>(G[0], G[1], b3);  xchg_dpp<0x128>(G[2], G[3], b3);   // row_ror:8 == xor8
    xchg_dpp<0x128>(G[4], G[5], b3);  xchg_dpp<0x128>(G[6], G[7], b3);
    pl16x(G[0], G[2]);  pl16x(G[1], G[3]);  pl16x(G[4], G[6]);  pl16x(G[5], G[7]);   // xor16
    pl32x(G[0], G[4]);  pl32x(G[1], G[5]);  pl32x(G[2], G[6]);  pl32x(G[3], G[7]);   // xor32
    dft8p_ip(G);                                   // DFT over q1 -> v1
#pragma unroll
    for (int m1 = 1; m1 < 8; ++m1) G[m1] = cmulv(G[m1], tB[m1]);   // W512^{8*q0*v1}
    // T2: reg digit (v1) <-> lane-low digit (q0): bits reg0<->lane0, reg1<->lane1, reg2<->lane2
    xchg_dpp<0xB1>(G[0], G[1], b0);  xchg_dpp<0xB1>(G[2], G[3], b0);     // quad_perm xor1
    xchg_dpp<0xB1>(G[4], G[5], b0);  xchg_dpp<0xB1>(G[6], G[7], b0);
    xchg_dpp<0x4E>(G[0], G[2], b1);  xchg_dpp<0x4E>(G[1], G[3], b1);     // quad_perm xor2
    xchg_dpp<0x4E>(G[4], G[6], b1);  xchg_dpp<0x4E>(G[5], G[7], b1);
    xchg_swz4(G[0], G[4], b2);  xchg_swz4(G[1], G[5], b2);               // ds_swizzle xor4
    xchg_swz4(G[2], G[6], b2);  xchg_swz4(G[3], G[7], b2);
    dft8p_ip(G);                                   // DFT over q0 -> v2
    __syncthreads();   // barrier alpha: prior step's gathers done before region reuse
    *(v4f*)(awBase +  0) = v4f{G[0].x, G[0].y, G[1].x, G[1].y};
    *(v4f*)(awBase + 16) = v4f{G[2].x, G[2].y, G[3].x, G[3].y};
    *(v4f*)(awBase + 32) = v4f{G[4].x, G[4].y, G[5].x, G[5].y};
    *(v4f*)(awBase + 48) = v4f{G[6].x, G[6].y, G[7].x, G[7].y};
    __syncthreads();   // barrier beta: all waves' T ready
    if (active) {
        float acc = 0.0f;
#pragma unroll
        for (int ww = 0; ww < RPB; ++ww) {
            v2f q = *(const v2f*)(ldsBase + ww * WREG + spos);
            acc = fmaf(q.x, ph[ww].x, fmaf(-q.y, ph[ww].y, acc));
        }
        pA[0] = acc;
    }
}

// ---------------- init kernels (run once, shuffle FFT) -------------------------------------------
__device__ __forceinline__ void cbfly(float& ar, float& ai, float& br, float& bi,
                                      float wr, float wi) {
    float dr = ar - br, di = ai - bi;
    ar = ar + br; ai = ai + bi;
    br = fmaf(dr, wr, -di * wi);
    bi = fmaf(dr, wi,  di * wr);
}

__device__ __forceinline__ void init_trig(float2* trig, int tid) {
    if (tid < 256) {
        float ang = (float)tid * (6.283185307179586f / 512.0f);
        float s, c;
        sincosf(ang, &s, &c);
        trig[tid] = make_float2(c, s);
    }
}

__device__ __forceinline__ void fft512_inv_lds(float* xr, float* xi, const float2* trig, int L) {
#pragma unroll
    for (int r = 0; r < 4; ++r) {
        float2 w = trig[(r << 6) + L];
        cbfly(xr[r], xi[r], xr[r + 4], xi[r + 4], w.x, w.y);
    }
    {
        float2 w0 = trig[L << 1];
        float2 w1 = trig[(64 + L) << 1];
        cbfly(xr[0], xi[0], xr[2], xi[2], w0.x, w0.y);
        cbfly(xr[1], xi[1], xr[3], xi[3], w1.x, w1.y);
        cbfly(xr[4], xi[4], xr[6], xi[6], w0.x, w0.y);
        cbfly(xr[5], xi[5], xr[7], xi[7], w1.x, w1.y);
    }
    {
        float2 w = trig[L << 2];
        cbfly(xr[0], xi[0], xr[1], xi[1], w.x, w.y);
        cbfly(xr[2], xi[2], xr[3], xi[3], w.x, w.y);
        cbfly(xr[4], xi[4], xr[5], xi[5], w.x, w.y);
        cbfly(xr[6], xi[6], xr[7], xi[7], w.x, w.y);
    }
#pragma unroll
    for (int s = 3; s <= 8; ++s) {
        const int half = 512 >> (s + 1);
        const int ex = (L & (half - 1)) << s;
        float2 w = trig[ex];
        const bool hi = (L & half) != 0;
        float wr = hi ? w.x : 1.0f;
        float wi = hi ? w.y : 0.0f;
        float sg = hi ? -1.0f : 1.0f;
#pragma unroll
        for (int r = 0; r < 8; ++r) {
            float orv = __shfl_xor(xr[r], half);
            float oiv = __shfl_xor(xi[r], half);
            float tr = fmaf(sg, xr[r], orv);
            float ti = fmaf(sg, xi[r], oiv);
            xr[r] = fmaf(tr, wr, -ti * wi);
            xi[r] = fmaf(tr, wi,  ti * wr);
        }
    }
}

__global__ __launch_bounds__(256) void f1_kernel(const float* __restrict__ f,
                                                 float2* __restrict__ R) {
    __shared__ float2 trig[256];
    const int tid = threadIdx.x;
    init_trig(trig, tid);
    __syncthreads();
    const int w = tid >> 6, L = tid & 63;
    const int x = 128 + blockIdx.x * 4 + w;   // nonzero rows only: [128, 384)
    const int b = blockIdx.y;
    const float* frow = f + ((size_t)b * 256 + (x - 128)) * 256;
    float xr[8], xi[8];
#pragma unroll
    for (int r = 0; r < 8; ++r) {
        int e = r * 64 + L;
        xr[r] = (e >= 128 && e < 384) ? frow[e - 128] : 0.0f;
        xi[r] = 0.0f;
    }
    fft512_inv_lds(xr, xi, trig, L);
    float2* Rrow = R + ((size_t)b * NOUT + x) * NOUT;
#pragma unroll
    for (int r = 0; r < 8; ++r) {
        int e = r * 64 + L;
        int k = __brev((unsigned)e) >> 23;
        Rrow[k] = make_float2(xr[r], -xi[r]);
    }
}

// f2: rows x outside [128,384) of R were never written (and are not zeroed) — treat as 0.
// e = r*64 + L is in [128,384) exactly for r in [2,6).
__global__ __launch_bounds__(256) void f2_kernel(const float2* __restrict__ R,
                                                 float2* __restrict__ A0) {
    __shared__ float2 trig[256];
    const int tid = threadIdx.x;
    init_trig(trig, tid);
    __syncthreads();
    const int w = tid >> 6, L = tid & 63;
    const int q = blockIdx.x * 4 + w;
    const int b = blockIdx.y;
    float xr[8], xi[8];
#pragma unroll
    for (int r = 0; r < 8; ++r) {
        if (r >= 2 && r < 6) {
            int e = r * 64 + L;
            float2 v = R[((size_t)b * NOUT + e) * NOUT + q];
            xr[r] = v.x;
            xi[r] = -v.y;
        } else {
            xr[r] = 0.0f;
            xi[r] = 0.0f;
        }
    }
    fft512_inv_lds(xr, xi, trig, L);
#pragma unroll
    for (int r = 0; r < 8; ++r) {
        int e = r * 64 + L;
        int p = __brev((unsigned)e) >> 23;
        A0[((size_t)b * NOUT + p) * NOUT + q] = make_float2(xr[r], -xi[r]);
    }
}

// ---------------- time-chunk simulation ----------------------------------------------------------
// block = (row group g of RPB rows, batch b); wave w owns row p = RPB*g + w, p in 0..257.
// Threads 0..255 each own one sensor, summing the block's RPB rows after barrier beta.
__global__ __launch_bounds__(384, 4) void sim_kernel(
    const float* __restrict__ fil,
    const int* __restrict__ idx0, const int* __restrict__ idx1,
    float2* __restrict__ stateCur, float2* __restrict__ statePrev,
    float* __restrict__ partial, int Tc, int firstChunk, int lastChunk)
{
    __shared__ __align__(16) char waveMem[RPB * WREG];   // 31104 B
    __shared__ float2 trig[256];                         //  2048 B -> 33152 B total

    const int tid = threadIdx.x;              // 0..383
    const int w = tid >> 6, L = tid & 63;
    const int g = blockIdx.x, b = blockIdx.y;
    const int p = g * RPB + w;                // 0..257

    if (tid < 256) {
        float ang = (float)tid * (6.283185307179586f / 512.0f);
        float s, c;
        sincosf(ang, &s, &c);
        trig[tid] = make_float2(c, s);
    }
    __syncthreads();

    // --- per-lane constant twiddles ---
    v2f tA[8], tB[8];
#pragma unroll
    for (int k1 = 1; k1 < 8; ++k1) tA[k1] = wlookup(trig, L * k1);
#pragma unroll
    for (int m1 = 1; m1 < 8; ++m1) tB[m1] = wlookup(trig, 8 * (L & 7) * m1);

    // --- transpose predicates (loop-invariant; land in SGPR masks) ---
    const bool b0 = (L & 1) != 0;
    const bool b1 = (L & 2) != 0;
    const bool b2 = (L & 4) != 0;
    const bool b3 = (L & 8) != 0;

    // --- sensor constants: thread tid<256 owns sensor j=tid ---
    const bool active = tid < 256;
    int spos = 0;
    v2f ph[RPB];
    if (active) {
        int u = idx0[tid];
        int v = idx1[tid];
        spos = ((v & 7) * 8 + ((v >> 3) & 7)) * 80 + (v >> 6) * 8;
        // Hermitian fold phase: p==0 -> 1, p==256 -> (-1)^u, p==257 -> 0, else 2*W512^{pu}
#pragma unroll
        for (int ww = 0; ww < RPB; ++ww) {
            int prow = g * RPB + ww;
            v2f a0;
            if (prow == 0)        a0 = v2f{1.0f, 0.0f};
            else if (prow == 256) a0 = v2f{(u & 1) ? -1.0f : 1.0f, 0.0f};
            else if (prow == 257) a0 = v2f{0.0f, 0.0f};
            else                  a0 = 2.0f * wlookup(trig, prow * u);
            ph[ww] = a0;
        }
    } else {
#pragma unroll
        for (int ww = 0; ww < RPB; ++ww) ph[ww] = v2f{0.0f, 0.0f};
    }

    // --- per-lane LDS publish base (immediate-offset addressing inside the loop) ---
    char* myA    = waveMem + w * WREG;
    char* awBase = myA + L * 80;                 // final T write (pitch 80, conflict-free)

    // --- load state + filter into registers ---
    v2f a[8], bb[8];
    float C[8];
    {
        const size_t rowBase = ((size_t)b * NOUT + p) * NOUT;
        const float* filRow = fil + (size_t)p * NOUT;
#pragma unroll
        for (int r = 0; r < 8; ++r) {
            int e = r * 64 + L;
            float2 a0 = stateCur[rowBase + e];
            a[r] = v2f{a0.x, a0.y};
            if (firstChunk) {
                bb[r] = a[r];
            } else {
                float2 a1 = statePrev[rowBase + e];
                bb[r] = v2f{a1.x, a1.y};
            }
            C[r] = fmaf(-4.0f, filRow[e], 2.0f);
        }
    }

    float* pOut = partial + ((size_t)g * Tc * NB + b) * NPHI + tid;

    for (int tl = 0; tl < Tc; tl += 2) {
        // step A: bb becomes A_{t+1}
#pragma unroll
        for (int r = 0; r < 8; ++r) bb[r] = v2f{C[r], C[r]} * a[r] - bb[r];
        fft_sample(bb, tA, tB, b0, b1, b2, b3, awBase,
                   waveMem, spos, ph, active, pOut);
        pOut += NB * NPHI;
        // step B: a becomes A_{t+2}
#pragma unroll
        for (int r = 0; r < 8; ++r) a[r] = v2f{C[r], C[r]} * bb[r] - a[r];
        fft_sample(a, tA, tB, b0, b1, b2, b3, awBase,
                   waveMem, spos, ph, active, pOut);
        pOut += NB * NPHI;
    }

    // --- save state for the next chunk (skipped when this is the last chunk) ---
    if (!lastChunk) {
        const size_t rowBase = ((size_t)b * NOUT + p) * NOUT;
#pragma unroll
        for (int r = 0; r < 8; ++r) {
            int e = r * 64 + L;
            stateCur[rowBase + e]  = make_float2(a[r].x, a[r].y);
            statePrev[rowBase + e] = make_float2(bb[r].x, bb[r].y);
        }
    }
}

// ---------------- reduce NGRP row-group partials -> out[b][j][t] ----------------------------------
__global__ __launch_bounds__(256) void reduce_kernel(const float* __restrict__ partial,
                                                     float* __restrict__ out,
                                                     int Tc, int tStart) {
    int id = blockIdx.x * 256 + threadIdx.x;   // over Tc*16*256, exact
    int j = id & 255;
    int b = (id >> 8) & 15;
    int tl = id >> 12;
    float s = 0.0f;
#pragma unroll
    for (int gg = 0; gg < NGRP; ++gg)
        s += partial[(((size_t)gg * Tc + tl) * NB + b) * NPHI + j];
    out[((size_t)b * NPHI + j) * NT + (tStart + tl)] = s * (1.0f / (512.0f * 512.0f));
}

extern "C" void kernel_launch(void* const* d_in, const int* in_sizes, int n_in,
                              void* d_out, int out_size, void* d_ws, size_t ws_size,
                              hipStream_t stream) {
    (void)in_sizes; (void)n_in; (void)out_size;
    const float* f   = (const float*)d_in[0];   // [16,1,256,256]
    const float* fil = (const float*)d_in[1];   // [512,512]
    const int* idx0  = (const int*)d_in[2];     // [256]
    const int* idx1  = (const int*)d_in[3];     // [256]
    float* out = (float*)d_out;                 // [16,1,256,240]

    char* ws = (char*)d_ws;
    const size_t stateBytes = (size_t)NB * NOUT * NOUT * sizeof(float2);  // 33.55 MB
    float2* stateCur  = (float2*)ws;
    float2* statePrev = (float2*)(ws + stateBytes);   // also reused as R scratch for f1/f2
    float*  partial   = (float*)(ws + 2 * stateBytes);
    size_t remain = (ws_size > 2 * stateBytes) ? ws_size - 2 * stateBytes : 0;

    // largest even time chunk whose partial buffer fits (even: the sim loop is 2-step unrolled)
    static const int tcs[] = {240, 120, 80, 60, 48, 40, 30, 24, 20, 16, 12, 10, 8, 6, 4, 2};
    int Tc = 2;
    for (int i = 0; i < 16; ++i) {
        size_t need = (size_t)NGRP * tcs[i] * NB * NPHI * sizeof(float);
        if (need <= remain) { Tc = tcs[i]; break; }
    }

    // no memset: f1 writes rows [128,384) of the R scratch; f2 skips the rest as known-zero
    f1_kernel<<<dim3(64, NB), 256, 0, stream>>>(f, statePrev);        // rows x in [128,384)
    f2_kernel<<<dim3(128, NB), 256, 0, stream>>>(statePrev, stateCur);
    for (int t0 = 0; t0 < NT; t0 += Tc) {
        int last = (t0 + Tc) >= NT ? 1 : 0;
        sim_kernel<<<dim3(NGRP, NB), RPB * 64, 0, stream>>>(fil, idx0, idx1, stateCur, statePrev,
                                                            partial, Tc, t0 == 0 ? 1 : 0, last);
        reduce_kernel<<<dim3(Tc * NB), 256, 0, stream>>>(partial, out, Tc, t0);
    }
}

// Round 3
// 950.185 us; speedup vs baseline: 1.0393x; 1.0255x over previous
//
#include <hip/hip_runtime.h>
#include <hip/hip_bf16.h>

// WaveOperator: Fourier-domain 3-term recurrence + per-row inverse FFT sampling.
// A_{t+1}(p,q) = (2-4*fil(p,q)) * A_t - A_{t-1};  y[b,j,t] = Re(ifft2(A_{t+1})[u_j,v_j])
// R19 (resubmit; previous round's bench failed on container acquisition, not the kernel):
//  - Sensors only read final-digit regs v>>6 in {2..5} (v in [130,382] by problem geometry),
//    so publish only G2..G5 (2x ds_write_b128 instead of 4) and compute only those 4 outputs
//    in the last dft8p layer.
//  - The freed 32 B/lane inside the pitch-80 region double-buffers the publish by step parity
//    -> barrier alpha (region-reuse guard) is unnecessary: gather(t) precedes barrier(t+1) in
//    every thread's program order, which orders it before publish(t+2) reuses the buffer.
//    One __syncthreads per time step instead of two.
// R18 history: in-register T1/T2 transposes (permlane/DPP/ds_swizzle) took conflicts 1.44e8 ->
// 1.71e7 and VALUBusy 39 -> 63%; sim 940 -> 917 us. Remaining idle is barrier/publish overhead.

#define NOUT 512
#define NB 16
#define NPHI 256
#define NT 240
#define RPB 6             // rows per block (= waves per block)
#define NGRP 43           // row groups: 43*6 = 258 = rows 0..257 (257 gets zero phase)

#define WREG 5184         // per-wave LDS publish region (pitch 80; lane uses 2x32B parity bufs)

typedef float v2f __attribute__((ext_vector_type(2)));
typedef float v4f __attribute__((ext_vector_type(4)));
typedef unsigned int v2u __attribute__((ext_vector_type(2)));

__device__ __forceinline__ v2f cmulv(v2f a, v2f b) {
    return v2f{fmaf(a.x, b.x, -a.y * b.y), fmaf(a.x, b.y, a.y * b.x)};
}
__device__ __forceinline__ v2f cmuliv(v2f a) { return v2f{-a.y, a.x}; }
__device__ __forceinline__ v2f cmulw8v(v2f a) {
    const float s = 0.70710678118654752f; return v2f{s * (a.x - a.y), s * (a.x + a.y)};
}
__device__ __forceinline__ v2f cmulw83v(v2f a) {
    const float s = 0.70710678118654752f; return v2f{-s * (a.x + a.y), s * (a.x - a.y)};
}

// 8-pt DFT, positive exponent: Y[k] = sum_r y[r] * exp(+2pi i rk/8)
__device__ __forceinline__ void dft8p(const v2f y[8], v2f Y[8]) {
    v2f t0 = y[0] + y[4], t4 = y[0] - y[4];
    v2f t1 = y[1] + y[5], t5 = cmulw8v(y[1] - y[5]);
    v2f t2 = y[2] + y[6], t6 = cmuliv(y[2] - y[6]);
    v2f t3 = y[3] + y[7], t7 = cmulw83v(y[3] - y[7]);
    v2f u0 = t0 + t2, u2 = t0 - t2;
    v2f u1 = t1 + t3, u3 = cmuliv(t1 - t3);
    Y[0] = u0 + u1; Y[4] = u0 - u1;
    Y[2] = u2 + u3; Y[6] = u2 - u3;
    v2f v0 = t4 + t6, v2 = t4 - t6;
    v2f v1 = t5 + t7, v3 = cmuliv(t5 - t7);
    Y[1] = v0 + v1; Y[5] = v0 - v1;
    Y[3] = v2 + v3; Y[7] = v2 - v3;
}

// in-place variant (t-layer fully buffers the inputs before any write)
__device__ __forceinline__ void dft8p_ip(v2f y[8]) {
    v2f t0 = y[0] + y[4], t4 = y[0] - y[4];
    v2f t1 = y[1] + y[5], t5 = cmulw8v(y[1] - y[5]);
    v2f t2 = y[2] + y[6], t6 = cmuliv(y[2] - y[6]);
    v2f t3 = y[3] + y[7], t7 = cmulw83v(y[3] - y[7]);
    v2f u0 = t0 + t2, u2 = t0 - t2;
    v2f u1 = t1 + t3, u3 = cmuliv(t1 - t3);
    y[0] = u0 + u1; y[4] = u0 - u1;
    y[2] = u2 + u3; y[6] = u2 - u3;
    v2f v0 = t4 + t6, v2 = t4 - t6;
    v2f v1 = t5 + t7, v3 = cmuliv(t5 - t7);
    y[1] = v0 + v1; y[5] = v0 - v1;
    y[3] = v2 + v3; y[7] = v2 - v3;
}

// final-layer DFT producing only outputs Y2,Y3,Y4,Y5 (the sensor v>>6 range)
__device__ __forceinline__ void dft8p_mid4(const v2f y[8], v2f o[4]) {
    v2f t0 = y[0] + y[4], t4 = y[0] - y[4];
    v2f t1 = y[1] + y[5], t5 = cmulw8v(y[1] - y[5]);
    v2f t2 = y[2] + y[6], t6 = cmuliv(y[2] - y[6]);
    v2f t3 = y[3] + y[7], t7 = cmulw83v(y[3] - y[7]);
    v2f u0 = t0 + t2, u2 = t0 - t2;
    v2f u1 = t1 + t3, u3 = cmuliv(t1 - t3);
    v2f w0 = t4 + t6, w2 = t4 - t6;
    v2f w1 = t5 + t7, w3 = cmuliv(t5 - t7);
    o[0] = u2 + u3;    // Y2
    o[1] = w2 + w3;    // Y3
    o[2] = u0 - u1;    // Y4
    o[3] = w0 - w1;    // Y5
}

// W512^m from half-table
__device__ __forceinline__ v2f wlookup(const float2* trig, int m) {
    m &= 511;
    float2 ph = trig[m & 255];
    return (m & 256) ? v2f{-ph.x, -ph.y} : v2f{ph.x, ph.y};
}

// ---- in-register lane exchanges (transpose building blocks) -------------------------------------
template<int CTRL>
__device__ __forceinline__ float dppx(float x) {
    return __int_as_float(__builtin_amdgcn_mov_dpp(__float_as_int(x), CTRL, 0xF, 0xF, true));
}
__device__ __forceinline__ float swzx4(float x) {
    // BitMode swizzle: and=0x1F, or=0, xor=4  -> lane ^ 4
    return __int_as_float(__builtin_amdgcn_ds_swizzle(__float_as_int(x), 0x101F));
}

template<int CTRL>
__device__ __forceinline__ void xchg_dpp(v2f& a, v2f& b, bool bit) {
    float sx = bit ? a.x : b.x;
    float sy = bit ? a.y : b.y;
    float tx = dppx<CTRL>(sx);
    float ty = dppx<CTRL>(sy);
    a.x = bit ? tx : a.x;   a.y = bit ? ty : a.y;
    b.x = bit ? b.x : tx;   b.y = bit ? b.y : ty;
}
__device__ __forceinline__ void xchg_swz4(v2f& a, v2f& b, bool bit) {
    float sx = bit ? a.x : b.x;
    float sy = bit ? a.y : b.y;
    float tx = swzx4(sx);
    float ty = swzx4(sy);
    a.x = bit ? tx : a.x;   a.y = bit ? ty : a.y;
    b.x = bit ? b.x : tx;   b.y = bit ? b.y : ty;
}

#if __has_builtin(__builtin_amdgcn_permlane16_swap)
__device__ __forceinline__ void pl16x(v2f& a, v2f& b) {
    v2u rx = __builtin_amdgcn_permlane16_swap(__float_as_uint(a.x), __float_as_uint(b.x), false, false);
    a.x = __uint_as_float(rx.x); b.x = __uint_as_float(rx.y);
    v2u ry = __builtin_amdgcn_permlane16_swap(__float_as_uint(a.y), __float_as_uint(b.y), false, false);
    a.y = __uint_as_float(ry.x); b.y = __uint_as_float(ry.y);
}
#else
__device__ __forceinline__ void pl16x(v2f& a, v2f& b) {
    bool bit = (threadIdx.x & 16) != 0;
    float sx = bit ? a.x : b.x, sy = bit ? a.y : b.y;
    float tx = __shfl_xor(sx, 16), ty = __shfl_xor(sy, 16);
    a.x = bit ? tx : a.x; a.y = bit ? ty : a.y;
    b.x = bit ? b.x : tx; b.y = bit ? b.y : ty;
}
#endif

#if __has_builtin(__builtin_amdgcn_permlane32_swap)
__device__ __forceinline__ void pl32x(v2f& a, v2f& b) {
    v2u rx = __builtin_amdgcn_permlane32_swap(__float_as_uint(a.x), __float_as_uint(b.x), false, false);
    a.x = __uint_as_float(rx.x); b.x = __uint_as_float(rx.y);
    v2u ry = __builtin_amdgcn_permlane32_swap(__float_as_uint(a.y), __float_as_uint(b.y), false, false);
    a.y = __uint_as_float(ry.x); b.y = __uint_as_float(ry.y);
}
#else
__device__ __forceinline__ void pl32x(v2f& a, v2f& b) {
    bool bit = (threadIdx.x & 32) != 0;
    float sx = bit ? a.x : b.x, sy = bit ? a.y : b.y;
    float tx = __shfl_xor(sx, 32), ty = __shfl_xor(sy, 32);
    a.x = bit ? tx : a.x; a.y = bit ? ty : a.y;
    b.x = bit ? b.x : tx; b.y = bit ? b.y : ty;
}
#endif

// hot-loop step: in-register 512-pt inverse DFT (8x8x8 four-step; transposes via
// permlane/DPP/swizzle), publish G2..G5 to this step's parity buffer, ONE barrier, gather.
// awBase/ldsBase carry the parity offset (0 or 32) folded in by the caller.
__device__ __forceinline__ void fft_sample(
    const v2f y[8], const v2f tA[8], const v2f tB[8],
    bool b0, bool b1, bool b2, bool b3,
    char* awBase, const char* ldsBase, int spos, const v2f ph[RPB], bool active,
    float* pA)
{
    v2f G[8];
    dft8p(y, G);                                   // DFT over q2 (reg digit) -> v0
#pragma unroll
    for (int k1 = 1; k1 < 8; ++k1) G[k1] = cmulv(G[k1], tA[k1]);   // W512^{L*v0}
    // T1: reg digit (v0) <-> lane-high digit (q1)
    xchg_dpp<0x128>(G[0], G[1], b3);  xchg_dpp<0x128>(G[2], G[3], b3);   // row_ror:8 == xor8
    xchg_dpp<0x128>(G[4], G[5], b3);  xchg_dpp<0x128>(G[6], G[7], b3);
    pl16x(G[0], G[2]);  pl16x(G[1], G[3]);  pl16x(G[4], G[6]);  pl16x(G[5], G[7]);   // xor16
    pl32x(G[0], G[4]);  pl32x(G[1], G[5]);  pl32x(G[2], G[6]);  pl32x(G[3], G[7]);   // xor32
    dft8p_ip(G);                                   // DFT over q1 -> v1
#pragma unroll
    for (int m1 = 1; m1 < 8; ++m1) G[m1] = cmulv(G[m1], tB[m1]);   // W512^{8*q0*v1}
    // T2: reg digit (v1) <-> lane-low digit (q0)
    xchg_dpp<0xB1>(G[0], G[1], b0);  xchg_dpp<0xB1>(G[2], G[3], b0);     // quad_perm xor1
    xchg_dpp<0xB1>(G[4], G[5], b0);  xchg_dpp<0xB1>(G[6], G[7], b0);
    xchg_dpp<0x4E>(G[0], G[2], b1);  xchg_dpp<0x4E>(G[1], G[3], b1);     // quad_perm xor2
    xchg_dpp<0x4E>(G[4], G[6], b1);  xchg_dpp<0x4E>(G[5], G[7], b1);
    xchg_swz4(G[0], G[4], b2);  xchg_swz4(G[1], G[5], b2);               // ds_swizzle xor4
    xchg_swz4(G[2], G[6], b2);  xchg_swz4(G[3], G[7], b2);
    v2f o[4];
    dft8p_mid4(G, o);                              // DFT over q0 -> v2 (only outputs 2..5)
    *(v4f*)(awBase +  0) = v4f{o[0].x, o[0].y, o[1].x, o[1].y};   // G2,G3
    *(v4f*)(awBase + 16) = v4f{o[2].x, o[2].y, o[3].x, o[3].y};   // G4,G5
    __syncthreads();   // single barrier: publish visible; orders prev gather vs buffer reuse
    if (active) {
        float acc = 0.0f;
#pragma unroll
        for (int ww = 0; ww < RPB; ++ww) {
            v2f q = *(const v2f*)(ldsBase + ww * WREG + spos);
            acc = fmaf(q.x, ph[ww].x, fmaf(-q.y, ph[ww].y, acc));
        }
        pA[0] = acc;
    }
}

// ---------------- init kernels (run once, shuffle FFT) -------------------------------------------
__device__ __forceinline__ void cbfly(float& ar, float& ai, float& br, float& bi,
                                      float wr, float wi) {
    float dr = ar - br, di = ai - bi;
    ar = ar + br; ai = ai + bi;
    br = fmaf(dr, wr, -di * wi);
    bi = fmaf(dr, wi,  di * wr);
}

__device__ __forceinline__ void init_trig(float2* trig, int tid) {
    if (tid < 256) {
        float ang = (float)tid * (6.283185307179586f / 512.0f);
        float s, c;
        sincosf(ang, &s, &c);
        trig[tid] = make_float2(c, s);
    }
}

__device__ __forceinline__ void fft512_inv_lds(float* xr, float* xi, const float2* trig, int L) {
#pragma unroll
    for (int r = 0; r < 4; ++r) {
        float2 w = trig[(r << 6) + L];
        cbfly(xr[r], xi[r], xr[r + 4], xi[r + 4], w.x, w.y);
    }
    {
        float2 w0 = trig[L << 1];
        float2 w1 = trig[(64 + L) << 1];
        cbfly(xr[0], xi[0], xr[2], xi[2], w0.x, w0.y);
        cbfly(xr[1], xi[1], xr[3], xi[3], w1.x, w1.y);
        cbfly(xr[4], xi[4], xr[6], xi[6], w0.x, w0.y);
        cbfly(xr[5], xi[5], xr[7], xi[7], w1.x, w1.y);
    }
    {
        float2 w = trig[L << 2];
        cbfly(xr[0], xi[0], xr[1], xi[1], w.x, w.y);
        cbfly(xr[2], xi[2], xr[3], xi[3], w.x, w.y);
        cbfly(xr[4], xi[4], xr[5], xi[5], w.x, w.y);
        cbfly(xr[6], xi[6], xr[7], xi[7], w.x, w.y);
    }
#pragma unroll
    for (int s = 3; s <= 8; ++s) {
        const int half = 512 >> (s + 1);
        const int ex = (L & (half - 1)) << s;
        float2 w = trig[ex];
        const bool hi = (L & half) != 0;
        float wr = hi ? w.x : 1.0f;
        float wi = hi ? w.y : 0.0f;
        float sg = hi ? -1.0f : 1.0f;
#pragma unroll
        for (int r = 0; r < 8; ++r) {
            float orv = __shfl_xor(xr[r], half);
            float oiv = __shfl_xor(xi[r], half);
            float tr = fmaf(sg, xr[r], orv);
            float ti = fmaf(sg, xi[r], oiv);
            xr[r] = fmaf(tr, wr, -ti * wi);
            xi[r] = fmaf(tr, wi,  ti * wr);
        }
    }
}

__global__ __launch_bounds__(256) void f1_kernel(const float* __restrict__ f,
                                                 float2* __restrict__ R) {
    __shared__ float2 trig[256];
    const int tid = threadIdx.x;
    init_trig(trig, tid);
    __syncthreads();
    const int w = tid >> 6, L = tid & 63;
    const int x = 128 + blockIdx.x * 4 + w;   // nonzero rows only: [128, 384)
    const int b = blockIdx.y;
    const float* frow = f + ((size_t)b * 256 + (x - 128)) * 256;
    float xr[8], xi[8];
#pragma unroll
    for (int r = 0; r < 8; ++r) {
        int e = r * 64 + L;
        xr[r] = (e >= 128 && e < 384) ? frow[e - 128] : 0.0f;
        xi[r] = 0.0f;
    }
    fft512_inv_lds(xr, xi, trig, L);
    float2* Rrow = R + ((size_t)b * NOUT + x) * NOUT;
#pragma unroll
    for (int r = 0; r < 8; ++r) {
        int e = r * 64 + L;
        int k = __brev((unsigned)e) >> 23;
        Rrow[k] = make_float2(xr[r], -xi[r]);
    }
}

// f2: rows x outside [128,384) of R were never written (and are not zeroed) — treat as 0.
// e = r*64 + L is in [128,384) exactly for r in [2,6).
__global__ __launch_bounds__(256) void f2_kernel(const float2* __restrict__ R,
                                                 float2* __restrict__ A0) {
    __shared__ float2 trig[256];
    const int tid = threadIdx.x;
    init_trig(trig, tid);
    __syncthreads();
    const int w = tid >> 6, L = tid & 63;
    const int q = blockIdx.x * 4 + w;
    const int b = blockIdx.y;
    float xr[8], xi[8];
#pragma unroll
    for (int r = 0; r < 8; ++r) {
        if (r >= 2 && r < 6) {
            int e = r * 64 + L;
            float2 v = R[((size_t)b * NOUT + e) * NOUT + q];
            xr[r] = v.x;
            xi[r] = -v.y;
        } else {
            xr[r] = 0.0f;
            xi[r] = 0.0f;
        }
    }
    fft512_inv_lds(xr, xi, trig, L);
#pragma unroll
    for (int r = 0; r < 8; ++r) {
        int e = r * 64 + L;
        int p = __brev((unsigned)e) >> 23;
        A0[((size_t)b * NOUT + p) * NOUT + q] = make_float2(xr[r], -xi[r]);
    }
}

// ---------------- time-chunk simulation ----------------------------------------------------------
// block = (row group g of RPB rows, batch b); wave w owns row p = RPB*g + w, p in 0..257.
// Threads 0..255 each own one sensor, summing the block's RPB rows after the step barrier.
__global__ __launch_bounds__(384, 4) void sim_kernel(
    const float* __restrict__ fil,
    const int* __restrict__ idx0, const int* __restrict__ idx1,
    float2* __restrict__ stateCur, float2* __restrict__ statePrev,
    float* __restrict__ partial, int Tc, int firstChunk, int lastChunk)
{
    __shared__ __align__(16) char waveMem[RPB * WREG];   // 31104 B
    __shared__ float2 trig[256];                         //  2048 B -> 33152 B total

    const int tid = threadIdx.x;              // 0..383
    const int w = tid >> 6, L = tid & 63;
    const int g = blockIdx.x, b = blockIdx.y;
    const int p = g * RPB + w;                // 0..257

    if (tid < 256) {
        float ang = (float)tid * (6.283185307179586f / 512.0f);
        float s, c;
        sincosf(ang, &s, &c);
        trig[tid] = make_float2(c, s);
    }
    __syncthreads();

    // --- per-lane constant twiddles ---
    v2f tA[8], tB[8];
#pragma unroll
    for (int k1 = 1; k1 < 8; ++k1) tA[k1] = wlookup(trig, L * k1);
#pragma unroll
    for (int m1 = 1; m1 < 8; ++m1) tB[m1] = wlookup(trig, 8 * (L & 7) * m1);

    // --- transpose predicates (loop-invariant; land in SGPR masks) ---
    const bool b0 = (L & 1) != 0;
    const bool b1 = (L & 2) != 0;
    const bool b2 = (L & 4) != 0;
    const bool b3 = (L & 8) != 0;

    // --- sensor constants: thread tid<256 owns sensor j=tid ---
    const bool active = tid < 256;
    int spos = 0;
    v2f ph[RPB];
    if (active) {
        int u = idx0[tid];
        int v = idx1[tid];
        // published regs are v>>6 in {2..5} at lane-local offsets 0,8,16,24 (parity 0)
        spos = ((v & 7) * 8 + ((v >> 3) & 7)) * 80 + ((v >> 6) * 8 - 16);
        // Hermitian fold phase: p==0 -> 1, p==256 -> (-1)^u, p==257 -> 0, else 2*W512^{pu}
#pragma unroll
        for (int ww = 0; ww < RPB; ++ww) {
            int prow = g * RPB + ww;
            v2f a0;
            if (prow == 0)        a0 = v2f{1.0f, 0.0f};
            else if (prow == 256) a0 = v2f{(u & 1) ? -1.0f : 1.0f, 0.0f};
            else if (prow == 257) a0 = v2f{0.0f, 0.0f};
            else                  a0 = 2.0f * wlookup(trig, prow * u);
            ph[ww] = a0;
        }
    } else {
#pragma unroll
        for (int ww = 0; ww < RPB; ++ww) ph[ww] = v2f{0.0f, 0.0f};
    }

    // --- per-lane LDS publish base; parity buffer offsets 0 / 32 within the pitch-80 slot ---
    char* myA    = waveMem + w * WREG;
    char* awBase = myA + L * 80;

    // --- load state + filter into registers ---
    v2f a[8], bb[8];
    float C[8];
    {
        const size_t rowBase = ((size_t)b * NOUT + p) * NOUT;
        const float* filRow = fil + (size_t)p * NOUT;
#pragma unroll
        for (int r = 0; r < 8; ++r) {
            int e = r * 64 + L;
            float2 a0 = stateCur[rowBase + e];
            a[r] = v2f{a0.x, a0.y};
            if (firstChunk) {
                bb[r] = a[r];
            } else {
                float2 a1 = statePrev[rowBase + e];
                bb[r] = v2f{a1.x, a1.y};
            }
            C[r] = fmaf(-4.0f, filRow[e], 2.0f);
        }
    }

    float* pOut = partial + ((size_t)g * Tc * NB + b) * NPHI + tid;

    for (int tl = 0; tl < Tc; tl += 2) {
        // step A (parity 0): bb becomes A_{t+1}
#pragma unroll
        for (int r = 0; r < 8; ++r) bb[r] = v2f{C[r], C[r]} * a[r] - bb[r];
        fft_sample(bb, tA, tB, b0, b1, b2, b3, awBase, waveMem,
                   spos, ph, active, pOut);
        pOut += NB * NPHI;
        // step B (parity 1): a becomes A_{t+2}
#pragma unroll
        for (int r = 0; r < 8; ++r) a[r] = v2f{C[r], C[r]} * bb[r] - a[r];
        fft_sample(a, tA, tB, b0, b1, b2, b3, awBase + 32, waveMem + 32,
                   spos, ph, active, pOut);
        pOut += NB * NPHI;
    }

    // --- save state for the next chunk (skipped when this is the last chunk) ---
    if (!lastChunk) {
        const size_t rowBase = ((size_t)b * NOUT + p) * NOUT;
#pragma unroll
        for (int r = 0; r < 8; ++r) {
            int e = r * 64 + L;
            stateCur[rowBase + e]  = make_float2(a[r].x, a[r].y);
            statePrev[rowBase + e] = make_float2(bb[r].x, bb[r].y);
        }
    }
}

// ---------------- reduce NGRP row-group partials -> out[b][j][t] ----------------------------------
__global__ __launch_bounds__(256) void reduce_kernel(const float* __restrict__ partial,
                                                     float* __restrict__ out,
                                                     int Tc, int tStart) {
    int id = blockIdx.x * 256 + threadIdx.x;   // over Tc*16*256, exact
    int j = id & 255;
    int b = (id >> 8) & 15;
    int tl = id >> 12;
    float s = 0.0f;
#pragma unroll
    for (int gg = 0; gg < NGRP; ++gg)
        s += partial[(((size_t)gg * Tc + tl) * NB + b) * NPHI + j];
    out[((size_t)b * NPHI + j) * NT + (tStart + tl)] = s * (1.0f / (512.0f * 512.0f));
}

extern "C" void kernel_launch(void* const* d_in, const int* in_sizes, int n_in,
                              void* d_out, int out_size, void* d_ws, size_t ws_size,
                              hipStream_t stream) {
    (void)in_sizes; (void)n_in; (void)out_size;
    const float* f   = (const float*)d_in[0];   // [16,1,256,256]
    const float* fil = (const float*)d_in[1];   // [512,512]
    const int* idx0  = (const int*)d_in[2];     // [256]
    const int* idx1  = (const int*)d_in[3];     // [256]
    float* out = (float*)d_out;                 // [16,1,256,240]

    char* ws = (char*)d_ws;
    const size_t stateBytes = (size_t)NB * NOUT * NOUT * sizeof(float2);  // 33.55 MB
    float2* stateCur  = (float2*)ws;
    float2* statePrev = (float2*)(ws + stateBytes);   // also reused as R scratch for f1/f2
    float*  partial   = (float*)(ws + 2 * stateBytes);
    size_t remain = (ws_size > 2 * stateBytes) ? ws_size - 2 * stateBytes : 0;

    // largest even time chunk whose partial buffer fits (even: the sim loop is 2-step unrolled)
    static const int tcs[] = {240, 120, 80, 60, 48, 40, 30, 24, 20, 16, 12, 10, 8, 6, 4, 2};
    int Tc = 2;
    for (int i = 0; i < 16; ++i) {
        size_t need = (size_t)NGRP * tcs[i] * NB * NPHI * sizeof(float);
        if (need <= remain) { Tc = tcs[i]; break; }
    }

    // no memset: f1 writes rows [128,384) of the R scratch; f2 skips the rest as known-zero
    f1_kernel<<<dim3(64, NB), 256, 0, stream>>>(f, statePrev);        // rows x in [128,384)
    f2_kernel<<<dim3(128, NB), 256, 0, stream>>>(statePrev, stateCur);
    for (int t0 = 0; t0 < NT; t0 += Tc) {
        int last = (t0 + Tc) >= NT ? 1 : 0;
        sim_kernel<<<dim3(NGRP, NB), RPB * 64, 0, stream>>>(fil, idx0, idx1, stateCur, statePrev,
                                                            partial, Tc, t0 == 0 ? 1 : 0, last);
        reduce_kernel<<<dim3(Tc * NB), 256, 0, stream>>>(partial, out, Tc, t0);
    }
}